// Round 11
// baseline (1015.095 us; speedup 1.0000x reference)
//
#include <hip/hip_runtime.h>
#include <hip/hip_bf16.h>

#define K_TOT 4096
#define N_TOT 11008
#define LDP 72

typedef __bf16 bf16x8 __attribute__((ext_vector_type(8)));
typedef float  f32x4  __attribute__((ext_vector_type(4)));
typedef float  f32x8  __attribute__((ext_vector_type(8)));

typedef __attribute__((address_space(1))) unsigned gu32;
typedef __attribute__((address_space(3))) unsigned lu32;

__device__ __forceinline__ void gload_lds16(const void* g, void* l) {
    __builtin_amdgcn_global_load_lds((gu32*)g, (lu32*)l, 16, 0, 0);
}

// ---------- prepass 1: dequant packed int4 -> bf16 W[N][K] ----------
__global__ __launch_bounds__(256)
void dequant_w(const int* __restrict__ Qw, const float* __restrict__ Sc,
               const float* __restrict__ Zr, __bf16* __restrict__ Wb)
{
    const int t   = blockIdx.x * 256 + threadIdx.x;
    const int c8  = t & (K_TOT / 8 - 1);
    const int r4  = t >> 9;
    const int kp0 = c8 * 8;
    const int n   = r4 * 4 + ((kp0 >> 4) & 3);
    const int kq  = kp0 >> 6;
    const int hf  = (kp0 >> 3) & 1;
    const int kb  = kq * 64 + hf * 32;

    const int4 wa = *(const int4*)(Qw + (size_t)r4 * K_TOT + kp0);
    const int4 wb = *(const int4*)(Qw + (size_t)r4 * K_TOT + kp0 + 4);
    const int g = kb >> 7;
    const float s = Sc[(size_t)g * N_TOT + n];
    const float z = Zr[(size_t)g * N_TOT + n];

    const int w8[8] = {wa.x, wa.y, wa.z, wa.w, wb.x, wb.y, wb.z, wb.w};
    bf16x8 ov[4];
    #pragma unroll
    for (int uu = 0; uu < 8; ++uu) {
        const unsigned v = (unsigned)w8[uu] & 0xFFFFu;
        #pragma unroll
        for (int i = 0; i < 4; ++i)
            ov[i][uu] = (__bf16)fmaf((float)((v >> (4 * i)) & 0xFu), s, z);
    }
    __bf16* o = Wb + (size_t)n * K_TOT + kb;
    #pragma unroll
    for (int i = 0; i < 4; ++i) *(bf16x8*)(o + i * 8) = ov[i];
}

// ---------- prepass 2: X f32 -> bf16 ----------
__global__ __launch_bounds__(256)
void convert_x(const float* __restrict__ X, __bf16* __restrict__ Xb, long total8)
{
    const long t = (long)blockIdx.x * 256 + threadIdx.x;
    if (t >= total8) return;
    f32x8 v = *(const f32x8*)(X + t * 8);
    bf16x8 o;
    #pragma unroll
    for (int j = 0; j < 8; ++j) o[j] = (__bf16)v[j];
    *(bf16x8*)(Xb + t * 8) = o;
}

// ---------- main: 128x128 tile, 4 waves of 64x64, dbuf 2x32KB -> 2 blocks/CU ----------
// r5-proven LDS algebra: [128 rows][64 k] bf16 (128B rows), read XOR (l15&7)<<4,
// staging via pre-swizzled global source + linear gload_lds dest. 0 bank conflicts.
// Counted vmcnt(8): tile t+1's 8 loads stay in flight across the barrier.
#define STG128(kt, dst) do {                                                     \
    const size_t ko_ = (size_t)(kt) * 64;                                        \
    _Pragma("unroll")                                                            \
    for (int j_ = 0; j_ < 4; ++j_) {                                             \
        gload_lds16(apg + j_ * 8 * (size_t)K_TOT + ko_,                          \
                    (dst) + (wid * 4 + j_) * 1024);                              \
        gload_lds16(bpg + j_ * 8 * (size_t)K_TOT + ko_,                          \
                    (dst) + 16384 + (wid * 4 + j_) * 1024);                      \
    }                                                                            \
} while (0)

__global__ __launch_bounds__(256, 2)
void gemm128db(const __bf16* __restrict__ A, const __bf16* __restrict__ B,
               const float* __restrict__ Bias, float* __restrict__ C, int gridM)
{
    extern __shared__ char lds_raw[];   // 2 x 32768

    const int tid  = threadIdx.x;
    const int lane = tid & 63;
    const int wid  = tid >> 6;          // 0..3
    const int l15  = lane & 15;
    const int lhi  = lane >> 4;

    // T1: bijective XCD swizzle (nwg % 8 == 0 guaranteed by host guard)
    const int nwg = gridDim.x;
    int wg = blockIdx.x;
    wg = (wg & 7) * (nwg >> 3) + (wg >> 3);
    const int bx  = wg % gridM;
    const int by  = wg / gridM;
    const int bm0 = bx * 128;
    const int bn0 = by * 128;

    const int wm = (wid >> 1) * 64;     // 0 / 64
    const int wn = (wid & 1) * 64;      // 0 / 64

    // staging source: chunk = 8 rows x 64 cols; lane -> row lane>>3, pre-swizzled col
    const int sr   = lane >> 3;
    const int scol = ((lane & 7) ^ sr) * 8;
    const __bf16* apg = A + (size_t)(bm0 + wid * 32 + sr) * K_TOT + scol;
    const __bf16* bpg = B + (size_t)(bn0 + wid * 32 + sr) * K_TOT + scol;

    char* cur = lds_raw;
    char* nxt = lds_raw + 32768;

    const unsigned rswz = (unsigned)((l15 & 7) << 4);

    f32x4 acc[4][4] = {};

    // prologue: stage tile 0
    STG128(0, cur);

    const int NT = K_TOT / 64;          // 64
    for (int t = 0; t < NT; ++t) {
        if (t + 1 < NT) {
            STG128(t + 1, nxt);
            asm volatile("s_waitcnt vmcnt(8)" ::: "memory");  // tile t landed; t+1 afloat
        } else {
            asm volatile("s_waitcnt vmcnt(0)" ::: "memory");
        }
        __builtin_amdgcn_s_barrier();
        __builtin_amdgcn_sched_barrier(0);

        #pragma unroll
        for (int kk = 0; kk < 2; ++kk) {
            const unsigned cb = ((unsigned)(kk * 64 + lhi * 16)) ^ rswz;
            bf16x8 af[4], bf[4];
            #pragma unroll
            for (int mi = 0; mi < 4; ++mi)
                af[mi] = *(const bf16x8*)(cur + (wm + mi * 16 + l15) * 128 + cb);
            #pragma unroll
            for (int ni = 0; ni < 4; ++ni)
                bf[ni] = *(const bf16x8*)(cur + 16384 + (wn + ni * 16 + l15) * 128 + cb);
            __builtin_amdgcn_s_setprio(1);
            #pragma unroll
            for (int mi = 0; mi < 4; ++mi)
                #pragma unroll
                for (int ni = 0; ni < 4; ++ni)
                    acc[mi][ni] = __builtin_amdgcn_mfma_f32_16x16x32_bf16(
                        af[mi], bf[ni], acc[mi][ni], 0, 0, 0);
            __builtin_amdgcn_s_setprio(0);
        }

        asm volatile("" ::: "memory");
        __builtin_amdgcn_s_barrier();       // reads of cur done before it is re-staged
        __builtin_amdgcn_sched_barrier(0);
        char* tmp = cur; cur = nxt; nxt = tmp;
    }

    // epilogue: C/D layout col=lane&15, row=(lane>>4)*4+reg (m89-verified)
    #pragma unroll
    for (int ni = 0; ni < 4; ++ni) {
        const int col = bn0 + wn + ni * 16 + l15;
        const float bv = Bias[col];
        #pragma unroll
        for (int mi = 0; mi < 4; ++mi) {
            const int row = bm0 + wm + mi * 16 + lhi * 4;
            #pragma unroll
            for (int r = 0; r < 4; ++r)
                C[(size_t)(row + r) * N_TOT + col] = acc[mi][ni][r] + bv;
        }
    }
}

// ---------- fallback: round-3 fused kernel ----------
__global__ __launch_bounds__(256)
void qgemm_fused(const float* __restrict__ X, const int* __restrict__ Qw,
                 const float* __restrict__ Sc, const float* __restrict__ Zr,
                 const float* __restrict__ Bias, float* __restrict__ C)
{
    __shared__ __bf16 As[128][LDP];
    __shared__ __bf16 Bs[128][LDP];

    const int tid  = threadIdx.x;
    const int lane = tid & 63;
    const int wid  = tid >> 6;
    const int l15  = lane & 15;
    const int lhi  = lane >> 4;

    const int bm0 = blockIdx.x * 128;
    const int bn0 = blockIdx.y * 128;
    const int wm  = (wid >> 1) * 64;
    const int wn  = (wid & 1) * 64;

    const int ar = tid >> 3;
    const int ac = (tid & 7) * 8;

    const int nl   = tid >> 1;
    const int half = tid & 1;
    const int n_g  = bn0 + nl;
    const int* qptr = Qw + (size_t)(n_g >> 2) * K_TOT + (nl & 3) * 16 + half * 8;
    const float* scp = Sc + n_g;
    const float* zrp = Zr + n_g;

    f32x4 acc[4][4] = {};

    for (int kt = 0; kt < K_TOT / 64; ++kt) {
        const int k0 = kt * 64;
        const int4 wa = *(const int4*)(qptr + k0);
        const int4 wb = *(const int4*)(qptr + k0 + 4);
        const float s = scp[(size_t)(kt >> 1) * N_TOT];
        const float z = zrp[(size_t)(kt >> 1) * N_TOT];

        f32x8 av[4];
        #pragma unroll
        for (int p = 0; p < 4; ++p)
            av[p] = *(const f32x8*)(X + (size_t)(bm0 + p * 32 + ar) * K_TOT + k0 + ac);

        const int w8[8] = {wa.x, wa.y, wa.z, wa.w, wb.x, wb.y, wb.z, wb.w};
        bf16x8 ov[4];
        #pragma unroll
        for (int uu = 0; uu < 8; ++uu) {
            const unsigned v = (unsigned)w8[uu] & 0xFFFFu;
            #pragma unroll
            for (int i = 0; i < 4; ++i)
                ov[i][uu] = (__bf16)fmaf((float)((v >> (4 * i)) & 0xFu), s, z);
        }
        #pragma unroll
        for (int p = 0; p < 4; ++p) {
            bf16x8 ab;
            #pragma unroll
            for (int j = 0; j < 8; ++j) ab[j] = (__bf16)av[p][j];
            *(bf16x8*)&As[p * 32 + ar][ac] = ab;
        }
        #pragma unroll
        for (int cc = 0; cc < 4; ++cc)
            *(bf16x8*)&Bs[nl][half * 32 + cc * 8] = ov[cc];

        __syncthreads();

        #pragma unroll
        for (int ks = 0; ks < 2; ++ks) {
            bf16x8 af[4], bfr[4];
            const int kc = ks * 32 + lhi * 8;
            #pragma unroll
            for (int mi = 0; mi < 4; ++mi)
                af[mi] = *(const bf16x8*)&As[wm + mi * 16 + l15][kc];
            #pragma unroll
            for (int ni = 0; ni < 4; ++ni)
                bfr[ni] = *(const bf16x8*)&Bs[wn + ni * 16 + l15][kc];
            #pragma unroll
            for (int mi = 0; mi < 4; ++mi)
                #pragma unroll
                for (int ni = 0; ni < 4; ++ni)
                    acc[mi][ni] = __builtin_amdgcn_mfma_f32_16x16x32_bf16(
                        af[mi], bfr[ni], acc[mi][ni], 0, 0, 0);
        }
        __syncthreads();
    }

    #pragma unroll
    for (int ni = 0; ni < 4; ++ni) {
        const int col = bn0 + wn + ni * 16 + l15;
        const float bv = Bias[col];
        #pragma unroll
        for (int mi = 0; mi < 4; ++mi) {
            const int row = bm0 + wm + mi * 16 + lhi * 4;
            #pragma unroll
            for (int r = 0; r < 4; ++r)
                C[(size_t)(row + r) * N_TOT + col] = acc[mi][ni][r] + bv;
        }
    }
}

extern "C" void kernel_launch(void* const* d_in, const int* in_sizes, int n_in,
                              void* d_out, int out_size, void* d_ws, size_t ws_size,
                              hipStream_t stream) {
    const float* X    = (const float*)d_in[0];
    const int*   Qw   = (const int*)d_in[1];
    const float* Sc   = (const float*)d_in[2];
    const float* Zr   = (const float*)d_in[3];
    const float* Bias = (const float*)d_in[4];
    float* C = (float*)d_out;

    const int M = in_sizes[0] / K_TOT;                 // 8192
    const size_t xb_bytes = (size_t)M * K_TOT * 2;
    const size_t wb_bytes = (size_t)N_TOT * K_TOT * 2;
    const size_t need = xb_bytes + wb_bytes;

    const int gridM = M / 128;                         // 64
    const int nwg   = gridM * (N_TOT / 128);           // 64*86 = 5504

    if (ws_size >= need && (M & 127) == 0 && (nwg & 7) == 0) {
        __bf16* Xb = (__bf16*)d_ws;
        __bf16* Wb = (__bf16*)((char*)d_ws + xb_bytes);

        const int nW = (N_TOT / 4) * (K_TOT / 8);
        dequant_w<<<nW / 256, 256, 0, stream>>>(Qw, Sc, Zr, Wb);

        const long total8 = (long)M * K_TOT / 8;
        convert_x<<<(int)((total8 + 255) / 256), 256, 0, stream>>>(X, Xb, total8);

        (void)hipFuncSetAttribute((const void*)gemm128db,
                                  hipFuncAttributeMaxDynamicSharedMemorySize, 65536);
        gemm128db<<<dim3(nwg), dim3(256), 65536, stream>>>(Xb, Wb, Bias, C, gridM);
    } else {
        dim3 grid(M / 128, N_TOT / 128);
        qgemm_fused<<<grid, dim3(256), 0, stream>>>(X, Qw, Sc, Zr, Bias, C);
    }
}

// Round 12
// 936.330 us; speedup vs baseline: 1.0841x; 1.0841x over previous
//
#include <hip/hip_runtime.h>
#include <hip/hip_bf16.h>

#define K_TOT 4096
#define N_TOT 11008
#define LDP 72

typedef __bf16 bf16x8 __attribute__((ext_vector_type(8)));
typedef float  f32x4  __attribute__((ext_vector_type(4)));
typedef float  f32x8  __attribute__((ext_vector_type(8)));

typedef __attribute__((address_space(1))) unsigned gu32;
typedef __attribute__((address_space(3))) unsigned lu32;

__device__ __forceinline__ void gload_lds16(const void* g, void* l) {
    __builtin_amdgcn_global_load_lds((gu32*)g, (lu32*)l, 16, 0, 0);
}

// ---------- prepass 1: dequant packed int4 -> bf16 W[N][K] ----------
__global__ __launch_bounds__(256)
void dequant_w(const int* __restrict__ Qw, const float* __restrict__ Sc,
               const float* __restrict__ Zr, __bf16* __restrict__ Wb)
{
    const int t   = blockIdx.x * 256 + threadIdx.x;
    const int c8  = t & (K_TOT / 8 - 1);
    const int r4  = t >> 9;
    const int kp0 = c8 * 8;
    const int n   = r4 * 4 + ((kp0 >> 4) & 3);
    const int kq  = kp0 >> 6;
    const int hf  = (kp0 >> 3) & 1;
    const int kb  = kq * 64 + hf * 32;

    const int4 wa = *(const int4*)(Qw + (size_t)r4 * K_TOT + kp0);
    const int4 wb = *(const int4*)(Qw + (size_t)r4 * K_TOT + kp0 + 4);
    const int g = kb >> 7;
    const float s = Sc[(size_t)g * N_TOT + n];
    const float z = Zr[(size_t)g * N_TOT + n];

    const int w8[8] = {wa.x, wa.y, wa.z, wa.w, wb.x, wb.y, wb.z, wb.w};
    bf16x8 ov[4];
    #pragma unroll
    for (int uu = 0; uu < 8; ++uu) {
        const unsigned v = (unsigned)w8[uu] & 0xFFFFu;
        #pragma unroll
        for (int i = 0; i < 4; ++i)
            ov[i][uu] = (__bf16)fmaf((float)((v >> (4 * i)) & 0xFu), s, z);
    }
    __bf16* o = Wb + (size_t)n * K_TOT + kb;
    #pragma unroll
    for (int i = 0; i < 4; ++i) *(bf16x8*)(o + i * 8) = ov[i];
}

// ---------- prepass 2: X f32 -> bf16 ----------
__global__ __launch_bounds__(256)
void convert_x(const float* __restrict__ X, __bf16* __restrict__ Xb, long total8)
{
    const long t = (long)blockIdx.x * 256 + threadIdx.x;
    if (t >= total8) return;
    f32x8 v = *(const f32x8*)(X + t * 8);
    bf16x8 o;
    #pragma unroll
    for (int j = 0; j < 8; ++j) o[j] = (__bf16)v[j];
    *(bf16x8*)(Xb + t * 8) = o;
}

// ---------- main: 256x256 BK=64, 8 waves, K-half-split LDS, 4-phase fine interleave ----------
// LDS buffer (64KB): A[2 kh][256 r][32 k] bf16 at 0, B same at +32768. Rows are 64B.
// Bank-exact swizzle: cell (r, slot) holds k-chunk slot ^ ((r>>1)&3); with 64B rows the
// row parity alternates 16-bank phases, and XOR-ing slot with row bits 1-2 puts exactly
// 2 lanes on each 4-bank group per 16-lane read -> wave64 minimum (free, m136).
// Phases per K-tile: (mh,kk) = (0,0) (1,0) (0,1) (1,1); each stages one half-tile of
// tile t+1 into nxt; vmcnt(4) gates at ph2/ph4 never drain (4 newer loads always afloat).
#define STG_A(kt, kh, bp) do {                                                    \
    const __bf16* g_ = apg + (size_t)(kt) * 64 + (kh) * 32;                       \
    gload_lds16(g_,                       (bp) + (kh) * 16384 + wid * 2048);      \
    gload_lds16(g_ + 16 * (size_t)K_TOT,  (bp) + (kh) * 16384 + wid * 2048 + 1024); \
} while (0)
#define STG_B(kt, kh, bp) do {                                                    \
    const __bf16* g_ = bpg + (size_t)(kt) * 64 + (kh) * 32;                       \
    gload_lds16(g_,                       (bp) + 32768 + (kh) * 16384 + wid * 2048); \
    gload_lds16(g_ + 16 * (size_t)K_TOT,  (bp) + 32768 + (kh) * 16384 + wid * 2048 + 1024); \
} while (0)

#define PH(MH, KK, READB, STGSTMT, GATESTMT)                                      \
  {                                                                               \
    bf16x8 af_[4];                                                                \
    _Pragma("unroll")                                                             \
    for (int j = 0; j < 4; ++j)                                                   \
      af_[j] = *(const bf16x8*)(cur + (KK) * 16384 +                              \
                 (wm + ((MH) * 4 + j) * 16 + l15) * 64 + sw4);                    \
    if (READB) {                                                                  \
      _Pragma("unroll")                                                           \
      for (int n = 0; n < 4; ++n)                                                 \
        bq[n] = *(const bf16x8*)(cur + 32768 + (KK) * 16384 +                     \
                  (wn + n * 16 + l15) * 64 + sw4);                                \
    }                                                                             \
    STGSTMT;                                                                      \
    __builtin_amdgcn_s_barrier();                                                 \
    asm volatile("s_waitcnt lgkmcnt(0)" ::: "memory");                            \
    __builtin_amdgcn_sched_barrier(0);                                            \
    __builtin_amdgcn_s_setprio(1);                                                \
    _Pragma("unroll")                                                             \
    for (int j = 0; j < 4; ++j) {                                                 \
      _Pragma("unroll")                                                           \
      for (int n = 0; n < 4; ++n)                                                 \
        acc[(MH) * 4 + j][n] = __builtin_amdgcn_mfma_f32_16x16x32_bf16(           \
            af_[j], bq[n], acc[(MH) * 4 + j][n], 0, 0, 0);                        \
    }                                                                             \
    __builtin_amdgcn_s_setprio(0);                                                \
    GATESTMT;                                                                     \
    __builtin_amdgcn_s_barrier();                                                 \
  }

#define VM4 asm volatile("s_waitcnt vmcnt(4)" ::: "memory")

__global__ __launch_bounds__(512, 1)
void gemm256p4(const __bf16* __restrict__ A, const __bf16* __restrict__ B,
               const float* __restrict__ Bias, float* __restrict__ C, int gridM)
{
    extern __shared__ char lds_raw[];   // 2 x 65536

    const int tid  = threadIdx.x;
    const int lane = tid & 63;
    const int wid  = tid >> 6;          // 0..7
    const int l15  = lane & 15;
    const int lhi  = lane >> 4;

    const int nwg = gridDim.x;
    int wg = blockIdx.x;
    wg = (wg & 7) * (nwg >> 3) + (wg >> 3);
    const int bx  = wg % gridM;
    const int by  = wg / gridM;
    const int bm0 = bx * 256;
    const int bn0 = by * 256;

    const int wm = (wid >> 2) * 128;    // 0 / 128
    const int wn = (wid & 3) * 64;      // 0/64/128/192

    // staging: per gload = 16 rows x 4 slots; lane -> row lane>>2, slot lane&3;
    // global k-chunk for (row, slot) = slot ^ ((row>>1)&3)  [bank-exact involution]
    const int srow  = lane >> 2;
    const int sslot = ((lane & 3) ^ ((srow >> 1) & 3)) * 8;
    const __bf16* apg = A + (size_t)(bm0 + wid * 32 + srow) * K_TOT + sslot;
    const __bf16* bpg = B + (size_t)(bn0 + wid * 32 + srow) * K_TOT + sslot;

    // read-side: physical slot = lhi ^ ((row>>1)&3); row ≡ l15 (mod 16) and the
    // 16-row base is a multiple of 16, so (row>>1)&3 == (l15>>1)&3 per lane.
    const int sw4 = ((lhi ^ ((l15 >> 1) & 3)) << 4);

    char* cur = lds_raw;
    char* nxt = lds_raw + 65536;

    f32x4 acc[8][4] = {};
    bf16x8 bq[4];

    // prologue: tile 0 kh0 (A,B) then kh1 (A,B); vmcnt(4) -> kh0 landed, kh1 afloat
    STG_A(0, 0, cur); STG_B(0, 0, cur);
    STG_A(0, 1, cur); STG_B(0, 1, cur);
    VM4;
    __builtin_amdgcn_s_barrier();

    const int NT = K_TOT / 64;          // 64
    for (int t = 0; t < NT; ++t) {
        const int kn = (t + 1 < NT) ? t + 1 : NT - 1;   // tail dup harmless
        PH(0, 0, true,  STG_A(kn, 0, nxt), (void)0)
        PH(1, 0, false, STG_B(kn, 0, nxt), VM4)         // gate: tile t kh1 landed
        PH(0, 1, true,  STG_A(kn, 1, nxt), (void)0)
        PH(1, 1, false, STG_B(kn, 1, nxt), VM4)         // gate: tile t+1 kh0 landed
        char* tmp = cur; cur = nxt; nxt = tmp;
    }

    // epilogue: C/D layout col=lane&15, row=(lane>>4)*4+reg (m89-verified)
    #pragma unroll
    for (int ni = 0; ni < 4; ++ni) {
        const int col = bn0 + wn + ni * 16 + l15;
        const float bv = Bias[col];
        #pragma unroll
        for (int mi = 0; mi < 8; ++mi) {
            const int row = bm0 + wm + mi * 16 + lhi * 4;
            #pragma unroll
            for (int r = 0; r < 4; ++r)
                C[(size_t)(row + r) * N_TOT + col] = acc[mi][ni][r] + bv;
        }
    }
}

// ---------- fallback: round-3 fused kernel ----------
__global__ __launch_bounds__(256)
void qgemm_fused(const float* __restrict__ X, const int* __restrict__ Qw,
                 const float* __restrict__ Sc, const float* __restrict__ Zr,
                 const float* __restrict__ Bias, float* __restrict__ C)
{
    __shared__ __bf16 As[128][LDP];
    __shared__ __bf16 Bs[128][LDP];

    const int tid  = threadIdx.x;
    const int lane = tid & 63;
    const int wid  = tid >> 6;
    const int l15  = lane & 15;
    const int lhi  = lane >> 4;

    const int bm0 = blockIdx.x * 128;
    const int bn0 = blockIdx.y * 128;
    const int wm  = (wid >> 1) * 64;
    const int wn  = (wid & 1) * 64;

    const int ar = tid >> 3;
    const int ac = (tid & 7) * 8;

    const int nl   = tid >> 1;
    const int half = tid & 1;
    const int n_g  = bn0 + nl;
    const int* qptr = Qw + (size_t)(n_g >> 2) * K_TOT + (nl & 3) * 16 + half * 8;
    const float* scp = Sc + n_g;
    const float* zrp = Zr + n_g;

    f32x4 acc[4][4] = {};

    for (int kt = 0; kt < K_TOT / 64; ++kt) {
        const int k0 = kt * 64;
        const int4 wa = *(const int4*)(qptr + k0);
        const int4 wb = *(const int4*)(qptr + k0 + 4);
        const float s = scp[(size_t)(kt >> 1) * N_TOT];
        const float z = zrp[(size_t)(kt >> 1) * N_TOT];

        f32x8 av[4];
        #pragma unroll
        for (int p = 0; p < 4; ++p)
            av[p] = *(const f32x8*)(X + (size_t)(bm0 + p * 32 + ar) * K_TOT + k0 + ac);

        const int w8[8] = {wa.x, wa.y, wa.z, wa.w, wb.x, wb.y, wb.z, wb.w};
        bf16x8 ov[4];
        #pragma unroll
        for (int uu = 0; uu < 8; ++uu) {
            const unsigned v = (unsigned)w8[uu] & 0xFFFFu;
            #pragma unroll
            for (int i = 0; i < 4; ++i)
                ov[i][uu] = (__bf16)fmaf((float)((v >> (4 * i)) & 0xFu), s, z);
        }
        #pragma unroll
        for (int p = 0; p < 4; ++p) {
            bf16x8 ab;
            #pragma unroll
            for (int j = 0; j < 8; ++j) ab[j] = (__bf16)av[p][j];
            *(bf16x8*)&As[p * 32 + ar][ac] = ab;
        }
        #pragma unroll
        for (int cc = 0; cc < 4; ++cc)
            *(bf16x8*)&Bs[nl][half * 32 + cc * 8] = ov[cc];

        __syncthreads();

        #pragma unroll
        for (int ks = 0; ks < 2; ++ks) {
            bf16x8 af[4], bfr[4];
            const int kc = ks * 32 + lhi * 8;
            #pragma unroll
            for (int mi = 0; mi < 4; ++mi)
                af[mi] = *(const bf16x8*)&As[wm + mi * 16 + l15][kc];
            #pragma unroll
            for (int ni = 0; ni < 4; ++ni)
                bfr[ni] = *(const bf16x8*)&Bs[wn + ni * 16 + l15][kc];
            #pragma unroll
            for (int mi = 0; mi < 4; ++mi)
                #pragma unroll
                for (int ni = 0; ni < 4; ++ni)
                    acc[mi][ni] = __builtin_amdgcn_mfma_f32_16x16x32_bf16(
                        af[mi], bfr[ni], acc[mi][ni], 0, 0, 0);
        }
        __syncthreads();
    }

    #pragma unroll
    for (int ni = 0; ni < 4; ++ni) {
        const int col = bn0 + wn + ni * 16 + l15;
        const float bv = Bias[col];
        #pragma unroll
        for (int mi = 0; mi < 4; ++mi) {
            const int row = bm0 + wm + mi * 16 + lhi * 4;
            #pragma unroll
            for (int r = 0; r < 4; ++r)
                C[(size_t)(row + r) * N_TOT + col] = acc[mi][ni][r] + bv;
        }
    }
}

extern "C" void kernel_launch(void* const* d_in, const int* in_sizes, int n_in,
                              void* d_out, int out_size, void* d_ws, size_t ws_size,
                              hipStream_t stream) {
    const float* X    = (const float*)d_in[0];
    const int*   Qw   = (const int*)d_in[1];
    const float* Sc   = (const float*)d_in[2];
    const float* Zr   = (const float*)d_in[3];
    const float* Bias = (const float*)d_in[4];
    float* C = (float*)d_out;

    const int M = in_sizes[0] / K_TOT;                 // 8192
    const size_t xb_bytes = (size_t)M * K_TOT * 2;
    const size_t wb_bytes = (size_t)N_TOT * K_TOT * 2;
    const size_t need = xb_bytes + wb_bytes;

    const int gridM = M / 256;
    const int nwg   = gridM * (N_TOT / 256);           // 32*43 = 1376

    if (ws_size >= need && (M & 255) == 0 && (nwg & 7) == 0) {
        __bf16* Xb = (__bf16*)d_ws;
        __bf16* Wb = (__bf16*)((char*)d_ws + xb_bytes);

        const int nW = (N_TOT / 4) * (K_TOT / 8);
        dequant_w<<<nW / 256, 256, 0, stream>>>(Qw, Sc, Zr, Wb);

        const long total8 = (long)M * K_TOT / 8;
        convert_x<<<(int)((total8 + 255) / 256), 256, 0, stream>>>(X, Xb, total8);

        (void)hipFuncSetAttribute((const void*)gemm256p4,
                                  hipFuncAttributeMaxDynamicSharedMemorySize, 131072);
        gemm256p4<<<dim3(nwg), dim3(512), 131072, stream>>>(Xb, Wb, Bias, C, gridM);
    } else {
        dim3 grid(M / 128, N_TOT / 128);
        qgemm_fused<<<grid, dim3(256), 0, stream>>>(X, Qw, Sc, Zr, Bias, C);
    }
}

// Round 15
// 927.564 us; speedup vs baseline: 1.0944x; 1.0095x over previous
//
#include <hip/hip_runtime.h>
#include <hip/hip_bf16.h>

#define K_TOT 4096
#define N_TOT 11008
#define LDP 72

typedef __bf16 bf16x8 __attribute__((ext_vector_type(8)));
typedef float  f32x4  __attribute__((ext_vector_type(4)));
typedef float  f32x8  __attribute__((ext_vector_type(8)));

typedef __attribute__((address_space(1))) unsigned gu32;
typedef __attribute__((address_space(3))) unsigned lu32;

__device__ __forceinline__ void gload_lds16(const void* g, void* l) {
    __builtin_amdgcn_global_load_lds((gu32*)g, (lu32*)l, 16, 0, 0);
}

// ---------- prepass 1: dequant packed int4 -> bf16 W[N][K] ----------
__global__ __launch_bounds__(256)
void dequant_w(const int* __restrict__ Qw, const float* __restrict__ Sc,
               const float* __restrict__ Zr, __bf16* __restrict__ Wb)
{
    const int t   = blockIdx.x * 256 + threadIdx.x;
    const int c8  = t & (K_TOT / 8 - 1);
    const int r4  = t >> 9;
    const int kp0 = c8 * 8;
    const int n   = r4 * 4 + ((kp0 >> 4) & 3);
    const int kq  = kp0 >> 6;
    const int hf  = (kp0 >> 3) & 1;
    const int kb  = kq * 64 + hf * 32;

    const int4 wa = *(const int4*)(Qw + (size_t)r4 * K_TOT + kp0);
    const int4 wb = *(const int4*)(Qw + (size_t)r4 * K_TOT + kp0 + 4);
    const int g = kb >> 7;
    const float s = Sc[(size_t)g * N_TOT + n];
    const float z = Zr[(size_t)g * N_TOT + n];

    const int w8[8] = {wa.x, wa.y, wa.z, wa.w, wb.x, wb.y, wb.z, wb.w};
    bf16x8 ov[4];
    #pragma unroll
    for (int uu = 0; uu < 8; ++uu) {
        const unsigned v = (unsigned)w8[uu] & 0xFFFFu;
        #pragma unroll
        for (int i = 0; i < 4; ++i)
            ov[i][uu] = (__bf16)fmaf((float)((v >> (4 * i)) & 0xFu), s, z);
    }
    __bf16* o = Wb + (size_t)n * K_TOT + kb;
    #pragma unroll
    for (int i = 0; i < 4; ++i) *(bf16x8*)(o + i * 8) = ov[i];
}

// ---------- prepass 2: X f32 -> bf16 ----------
__global__ __launch_bounds__(256)
void convert_x(const float* __restrict__ X, __bf16* __restrict__ Xb, long total8)
{
    const long t = (long)blockIdx.x * 256 + threadIdx.x;
    if (t >= total8) return;
    f32x8 v = *(const f32x8*)(X + t * 8);
    bf16x8 o;
    #pragma unroll
    for (int j = 0; j < 8; ++j) o[j] = (__bf16)v[j];
    *(bf16x8*)(Xb + t * 8) = o;
}

// ---------- main: 256x256 BK=64, 8 waves, 8-phase read-ahead schedule ----------
// LDS: buf0/buf1 (one K-tile each, 64KB): A[2 kk][256 r][32 k] at 0, B same at +32768.
// r12 bank-exact swizzle (measured 0 conflicts): cell slot XOR (row>>1)&3, both sides.
// Schedule per iter (tiles P=2i in buf0, Q=2i+1 in buf1; R=P+2, S=Q+2):
//   phase p issues ds_reads for phase p+1's MFMA; lgkmcnt(n) after the barrier waits
//   exactly the PREVIOUS phase's reads (one full phase of latency cover).
//   Stages: ph1 Q.B0 | ph2 Q.B1 | ph3 R.A0 | ph4 R.A1 | ph5 R.B0 | ph6 R.B1 | ph7 S.A0 | ph8 S.A1
//   Gates: vmcnt(2) at ph4/ph8 only; iteration-entry invariant: outstanding = Q.A (4).
// r13 fix: prologue also stages tile 1's A (no prev ph7/ph8 exists for i=0); gate vmcnt(4).
// r14 fix: in ph4/ph8 the new-buffer reads must come AFTER the phase barrier —
//   vmcnt is per-wave, so gate(VM2) -> barrier -> read is required for cross-wave
//   publication (r5-r12 invariant). Reads before the barrier raced other waves' DMA.
#define STG_A(kt, kh, bp) do {                                                    \
    const __bf16* g_ = apg + (size_t)(kt) * 64 + (kh) * 32;                       \
    gload_lds16(g_,                       (bp) + (kh) * 16384 + wid * 2048);      \
    gload_lds16(g_ + 16 * (size_t)K_TOT,  (bp) + (kh) * 16384 + wid * 2048 + 1024); \
} while (0)
#define STG_B(kt, kh, bp) do {                                                    \
    const __bf16* g_ = bpg + (size_t)(kt) * 64 + (kh) * 32;                       \
    gload_lds16(g_,                       (bp) + 32768 + (kh) * 16384 + wid * 2048); \
    gload_lds16(g_ + 16 * (size_t)K_TOT,  (bp) + 32768 + (kh) * 16384 + wid * 2048 + 1024); \
} while (0)

#define RD_A(dst, buf, G0)                                                        \
    _Pragma("unroll")                                                             \
    for (int j_ = 0; j_ < 4; ++j_)                                                \
      _Pragma("unroll")                                                           \
      for (int kk_ = 0; kk_ < 2; ++kk_)                                           \
        dst[j_][kk_] = *(const bf16x8*)((buf) + kk_ * 16384 +                     \
                        (wm + ((G0) + j_) * 16 + l15) * 64 + sw4);

#define RD_B(dst, buf, N0)                                                        \
    _Pragma("unroll")                                                             \
    for (int n_ = 0; n_ < 2; ++n_)                                                \
      _Pragma("unroll")                                                           \
      for (int kk_ = 0; kk_ < 2; ++kk_)                                           \
        dst[n_][kk_] = *(const bf16x8*)((buf) + 32768 + kk_ * 16384 +             \
                        (wn + ((N0) + n_) * 16 + l15) * 64 + sw4);

#define MM(R0, C0, Aset, Bset)                                                    \
    __builtin_amdgcn_s_setprio(1);                                                \
    _Pragma("unroll")                                                             \
    for (int mi_ = 0; mi_ < 4; ++mi_)                                             \
      _Pragma("unroll")                                                           \
      for (int n_ = 0; n_ < 2; ++n_)                                              \
        _Pragma("unroll")                                                         \
        for (int kk_ = 0; kk_ < 2; ++kk_)                                         \
          acc[(R0) + mi_][(C0) + n_] = __builtin_amdgcn_mfma_f32_16x16x32_bf16(   \
              Aset[mi_][kk_], Bset[n_][kk_], acc[(R0) + mi_][(C0) + n_], 0, 0, 0);\
    __builtin_amdgcn_s_setprio(0);

#define BAR      __builtin_amdgcn_s_barrier()
#define SBAR     __builtin_amdgcn_sched_barrier(0)
#define LGKM(n)  asm volatile("s_waitcnt lgkmcnt(" #n ")" ::: "memory")
#define VM2      asm volatile("s_waitcnt vmcnt(2)" ::: "memory")

__global__ __launch_bounds__(512, 1)
void gemm256ra(const __bf16* __restrict__ A, const __bf16* __restrict__ B,
               const float* __restrict__ Bias, float* __restrict__ C, int gridM)
{
    extern __shared__ char lds_raw[];   // 2 x 65536

    const int tid  = threadIdx.x;
    const int lane = tid & 63;
    const int wid  = tid >> 6;          // 0..7
    const int l15  = lane & 15;
    const int lhi  = lane >> 4;

    const int nwg = gridDim.x;
    int wg = blockIdx.x;
    wg = (wg & 7) * (nwg >> 3) + (wg >> 3);
    const int bx  = wg % gridM;
    const int by  = wg / gridM;
    const int bm0 = bx * 256;
    const int bn0 = by * 256;

    const int wm = (wid >> 2) * 128;    // 0 / 128
    const int wn = (wid & 3) * 64;      // 0/64/128/192

    // staging (r12-proven): lane -> row lane>>2, slot (lane&3)^((row>>1)&3)
    const int srow  = lane >> 2;
    const int sslot = ((lane & 3) ^ ((srow >> 1) & 3)) * 8;
    const __bf16* apg = A + (size_t)(bm0 + wid * 32 + srow) * K_TOT + sslot;
    const __bf16* bpg = B + (size_t)(bn0 + wid * 32 + srow) * K_TOT + sslot;

    // read-side swizzle (r12-proven, 0 conflicts)
    const int sw4 = ((lhi ^ ((l15 >> 1) & 3)) << 4);

    char* buf0 = lds_raw;
    char* buf1 = lds_raw + 65536;

    f32x4 acc[8][4] = {};
    bf16x8 a0[4][2], a1[4][2], b0[2][2], b1[2][2];

    // prologue: stage tile 0 fully into buf0 AND tile 1's A into buf1;
    // vmcnt(4) -> tile 0's 8 loads landed, tile 1's A (4 loads) afloat
    STG_A(0, 0, buf0); STG_A(0, 1, buf0);
    STG_B(0, 0, buf0); STG_B(0, 1, buf0);
    STG_A(1, 0, buf1); STG_A(1, 1, buf1);
    asm volatile("s_waitcnt vmcnt(4)" ::: "memory");
    BAR;
    RD_A(a0, buf0, 0);
    RD_B(b0, buf0, 0);

    const int NT  = K_TOT / 64;         // 64
    const int NIT = NT / 2;             // 32
    for (int i = 0; i < NIT; ++i) {
        const int tQ = 2 * i + 1;
        const int tR = (2 * i + 2 < NT) ? 2 * i + 2 : NT - 1;
        const int tS = (2 * i + 3 < NT) ? 2 * i + 3 : NT - 1;

        // ph1: q1(P) | reads for q2(P): A1 set
        RD_A(a1, buf0, 4);
        STG_B(tQ, 0, buf1);
        BAR; LGKM(8); SBAR;
        MM(0, 0, a0, b0);
        // ph2: q2(P) | reads for q3(P): B1 set
        RD_B(b1, buf0, 2);
        STG_B(tQ, 1, buf1);
        BAR; LGKM(4); SBAR;
        MM(4, 0, a1, b0);
        // ph3: q3(P) | no reads (q4 operands held)
        STG_A(tR, 0, buf0);
        BAR; LGKM(0); SBAR;
        MM(4, 2, a1, b1);
        // ph4: q4(P) | gate Q, publish via barrier, THEN read q1(Q): A1,B0 sets
        VM2;
        STG_A(tR, 1, buf0);
        BAR;
        RD_A(a1, buf1, 0);
        RD_B(b0, buf1, 0);
        LGKM(12); SBAR;
        MM(0, 2, a0, b1);
        // ph5: q1(Q) | reads for q2(Q): A0 set
        RD_A(a0, buf1, 4);
        STG_B(tR, 0, buf0);
        BAR; LGKM(8); SBAR;
        MM(0, 0, a1, b0);
        // ph6: q2(Q) | reads for q3(Q): B1 set
        RD_B(b1, buf1, 2);
        STG_B(tR, 1, buf0);
        BAR; LGKM(4); SBAR;
        MM(4, 0, a0, b0);
        // ph7: q3(Q) | no reads
        STG_A(tS, 0, buf1);
        BAR; LGKM(0); SBAR;
        MM(4, 2, a0, b1);
        // ph8: q4(Q) | gate P', publish via barrier, THEN read q1(P'): A0,B0 sets
        VM2;
        STG_A(tS, 1, buf1);
        BAR;
        RD_A(a0, buf0, 0);
        RD_B(b0, buf0, 0);
        LGKM(12); SBAR;
        MM(0, 2, a1, b1);
    }

    // epilogue: C/D layout col=lane&15, row=(lane>>4)*4+reg (m89-verified)
    #pragma unroll
    for (int ni = 0; ni < 4; ++ni) {
        const int col = bn0 + wn + ni * 16 + l15;
        const float bv = Bias[col];
        #pragma unroll
        for (int mi = 0; mi < 8; ++mi) {
            const int row = bm0 + wm + mi * 16 + lhi * 4;
            #pragma unroll
            for (int r = 0; r < 4; ++r)
                C[(size_t)(row + r) * N_TOT + col] = acc[mi][ni][r] + bv;
        }
    }
}

// ---------- fallback: round-3 fused kernel ----------
__global__ __launch_bounds__(256)
void qgemm_fused(const float* __restrict__ X, const int* __restrict__ Qw,
                 const float* __restrict__ Sc, const float* __restrict__ Zr,
                 const float* __restrict__ Bias, float* __restrict__ C)
{
    __shared__ __bf16 As[128][LDP];
    __shared__ __bf16 Bs[128][LDP];

    const int tid  = threadIdx.x;
    const int lane = tid & 63;
    const int wid  = tid >> 6;
    const int l15  = lane & 15;
    const int lhi  = lane >> 4;

    const int bm0 = blockIdx.x * 128;
    const int bn0 = blockIdx.y * 128;
    const int wm  = (wid >> 1) * 64;
    const int wn  = (wid & 1) * 64;

    const int ar = tid >> 3;
    const int ac = (tid & 7) * 8;

    const int nl   = tid >> 1;
    const int half = tid & 1;
    const int n_g  = bn0 + nl;
    const int* qptr = Qw + (size_t)(n_g >> 2) * K_TOT + (nl & 3) * 16 + half * 8;
    const float* scp = Sc + n_g;
    const float* zrp = Zr + n_g;

    f32x4 acc[4][4] = {};

    for (int kt = 0; kt < K_TOT / 64; ++kt) {
        const int k0 = kt * 64;
        const int4 wa = *(const int4*)(qptr + k0);
        const int4 wb = *(const int4*)(qptr + k0 + 4);
        const float s = scp[(size_t)(kt >> 1) * N_TOT];
        const float z = zrp[(size_t)(kt >> 1) * N_TOT];

        f32x8 av[4];
        #pragma unroll
        for (int p = 0; p < 4; ++p)
            av[p] = *(const f32x8*)(X + (size_t)(bm0 + p * 32 + ar) * K_TOT + k0 + ac);

        const int w8[8] = {wa.x, wa.y, wa.z, wa.w, wb.x, wb.y, wb.z, wb.w};
        bf16x8 ov[4];
        #pragma unroll
        for (int uu = 0; uu < 8; ++uu) {
            const unsigned v = (unsigned)w8[uu] & 0xFFFFu;
            #pragma unroll
            for (int i = 0; i < 4; ++i)
                ov[i][uu] = (__bf16)fmaf((float)((v >> (4 * i)) & 0xFu), s, z);
        }
        #pragma unroll
        for (int p = 0; p < 4; ++p) {
            bf16x8 ab;
            #pragma unroll
            for (int j = 0; j < 8; ++j) ab[j] = (__bf16)av[p][j];
            *(bf16x8*)&As[p * 32 + ar][ac] = ab;
        }
        #pragma unroll
        for (int cc = 0; cc < 4; ++cc)
            *(bf16x8*)&Bs[nl][half * 32 + cc * 8] = ov[cc];

        __syncthreads();

        #pragma unroll
        for (int ks = 0; ks < 2; ++ks) {
            bf16x8 af[4], bfr[4];
            const int kc = ks * 32 + lhi * 8;
            #pragma unroll
            for (int mi = 0; mi < 4; ++mi)
                af[mi] = *(const bf16x8*)&As[wm + mi * 16 + l15][kc];
            #pragma unroll
            for (int ni = 0; ni < 4; ++ni)
                bfr[ni] = *(const bf16x8*)&Bs[wn + ni * 16 + l15][kc];
            #pragma unroll
            for (int mi = 0; mi < 4; ++mi)
                #pragma unroll
                for (int ni = 0; ni < 4; ++ni)
                    acc[mi][ni] = __builtin_amdgcn_mfma_f32_16x16x32_bf16(
                        af[mi], bfr[ni], acc[mi][ni], 0, 0, 0);
        }
        __syncthreads();
    }

    #pragma unroll
    for (int ni = 0; ni < 4; ++ni) {
        const int col = bn0 + wn + ni * 16 + l15;
        const float bv = Bias[col];
        #pragma unroll
        for (int mi = 0; mi < 4; ++mi) {
            const int row = bm0 + wm + mi * 16 + lhi * 4;
            #pragma unroll
            for (int r = 0; r < 4; ++r)
                C[(size_t)(row + r) * N_TOT + col] = acc[mi][ni][r] + bv;
        }
    }
}

extern "C" void kernel_launch(void* const* d_in, const int* in_sizes, int n_in,
                              void* d_out, int out_size, void* d_ws, size_t ws_size,
                              hipStream_t stream) {
    const float* X    = (const float*)d_in[0];
    const int*   Qw   = (const int*)d_in[1];
    const float* Sc   = (const float*)d_in[2];
    const float* Zr   = (const float*)d_in[3];
    const float* Bias = (const float*)d_in[4];
    float* C = (float*)d_out;

    const int M = in_sizes[0] / K_TOT;                 // 8192
    const size_t xb_bytes = (size_t)M * K_TOT * 2;
    const size_t wb_bytes = (size_t)N_TOT * K_TOT * 2;
    const size_t need = xb_bytes + wb_bytes;

    const int gridM = M / 256;
    const int nwg   = gridM * (N_TOT / 256);           // 32*43 = 1376

    if (ws_size >= need && (M & 255) == 0 && (nwg & 7) == 0) {
        __bf16* Xb = (__bf16*)d_ws;
        __bf16* Wb = (__bf16*)((char*)d_ws + xb_bytes);

        const int nW = (N_TOT / 4) * (K_TOT / 8);
        dequant_w<<<nW / 256, 256, 0, stream>>>(Qw, Sc, Zr, Wb);

        const long total8 = (long)M * K_TOT / 8;
        convert_x<<<(int)((total8 + 255) / 256), 256, 0, stream>>>(X, Xb, total8);

        (void)hipFuncSetAttribute((const void*)gemm256ra,
                                  hipFuncAttributeMaxDynamicSharedMemorySize, 131072);
        gemm256ra<<<dim3(nwg), dim3(512), 131072, stream>>>(Xb, Wb, Bias, C, gridM);
    } else {
        dim3 grid(M / 128, N_TOT / 128);
        qgemm_fused<<<grid, dim3(256), 0, stream>>>(X, Qw, Sc, Zr, Bias, C);
    }
}